// Round 17
// baseline (125.793 us; speedup 1.0000x reference)
//
#include <hip/hip_runtime.h>

// FlashCRA on MI355X — round 17: REVERT to round-15 (last passing, 125.6us).
// Round-16's bundle (ones-MFMA lsum + vectorized transpose) failed correctness
// (absmax 1.8e-2); cause not cleanly attributable -> full revert per rigor rules.

typedef __bf16 bf16;
typedef __bf16 bf16x8 __attribute__((ext_vector_type(8)));
typedef __bf16 bf16x4 __attribute__((ext_vector_type(4)));
typedef float f32x4 __attribute__((ext_vector_type(4)));
typedef float f32x16 __attribute__((ext_vector_type(16)));
typedef unsigned int u32;

__device__ __forceinline__ bf16 f2bf(float f) {
  unsigned u = __builtin_bit_cast(unsigned, f);
  u += 0x7FFFu + ((u >> 16) & 1u);            // RNE, inputs finite
  unsigned short h = (unsigned short)(u >> 16);
  return __builtin_bit_cast(bf16, h);
}

__device__ __forceinline__ void gload_lds16(const bf16* g, bf16* l) {
  __builtin_amdgcn_global_load_lds((const __attribute__((address_space(1))) u32*)(const void*)g,
                                   (__attribute__((address_space(3))) u32*)(void*)l, 16, 0, 0);
}

__device__ __forceinline__ u32 cvtpk_bf16(float lo, float hi) {
  u32 r;
  asm("v_cvt_pk_bf16_f32 %0, %1, %2" : "=v"(r) : "v"(lo), "v"(hi));
  return r;
}
__device__ __forceinline__ void perm32swap(u32& a, u32& b) {
  asm("v_permlane32_swap_b32 %0, %1" : "+v"(a), "+v"(b));
}

#if __has_builtin(__builtin_amdgcn_exp2f)
#define EXP2(x) __builtin_amdgcn_exp2f(x)
#else
#define EXP2(x) exp2f(x)
#endif

// SCALE * log2(e), folded into Q at pack time
#define QSCALE 0.18033688f

// XCD-chunked bijective remap (requires gridDim.x*gridDim.y % 8 == 0)
__device__ __forceinline__ void xcd_remap(int& bx, int& by) {
  const int nx = gridDim.x;
  const int nwg = nx * gridDim.y;
  const int lin = blockIdx.y * nx + blockIdx.x;
  const int chunk = nwg >> 3;
  const int nid = (lin & 7) * chunk + (lin >> 3);
  bx = nid % nx;
  by = nid / nx;
}

// ---------------- merged prep: x,p fp32->bf16 + 3 weight transposes ----------------
__global__ __launch_bounds__(256) void k_prep(const float* __restrict__ x, bf16* __restrict__ xb,
                                              const float* __restrict__ p, bf16* __restrict__ pb,
                                              const float* __restrict__ W1, bf16* __restrict__ O1,
                                              const float* __restrict__ W2, bf16* __restrict__ O2,
                                              const float* __restrict__ W3, bf16* __restrict__ O3) {
  const int gb = blockIdx.x;
  if (gb < 8192) {
    int i = gb * 256 + threadIdx.x;
    const float* in = x; bf16* out = xb;
    if (i >= 1048576) { in = p; out = pb; i -= 1048576; }
    const float4 v = ((const float4*)in)[i];
    bf16x4 o;
    o[0] = f2bf(v.x); o[1] = f2bf(v.y); o[2] = f2bf(v.z); o[3] = f2bf(v.w);
    *(bf16x4*)(out + (size_t)i * 4) = o;
    return;
  }
  __shared__ float t[64][65];
  const int lin = gb - 8192;
  int bx = lin % 72;
  const int by = lin / 72;
  const float* in; bf16* out; int C;
  if (bx < 48)      { in = W1; out = O1; C = 3072; }
  else if (bx < 56) { in = W2; out = O2; C = 512;  bx -= 48; }
  else              { in = W3; out = O3; C = 1024; bx -= 56; }
  const int R = 1024;
  const int c0 = bx * 64, r0 = by * 64;
  for (int e = threadIdx.x; e < 4096; e += 256) {
    int r = e >> 6, c = e & 63;
    t[r][c] = in[(size_t)(r0 + r) * C + c0 + c];
  }
  __syncthreads();
  for (int e = threadIdx.x; e < 4096; e += 256) {
    int c = e >> 6, r = e & 63;
    out[(size_t)(c0 + c) * R + r0 + r] = f2bf(t[r][c]);
  }
}

// ---------------- C[M][N] = A @ Bt^T + bias — 128x64 tile, 8 waves, 2 blocks/CU ----------------
__global__ __launch_bounds__(512, 4) void k_gemm128x64(const bf16* __restrict__ A,
                                                       const bf16* __restrict__ Bt,
                                                       const float* __restrict__ bias,
                                                       float* __restrict__ C,
                                                       int M, int N, int K) {
  __shared__ bf16 sA0[8192], sA1[8192];       // 128 x 64
  __shared__ bf16 sB0[4096], sB1[4096];       // 64 x 64
  const int tid = threadIdx.x;
  const int lane = tid & 63, w = tid >> 6;
  const int lrow = lane & 15, lgrp = lane >> 4;
  const int wm = (w >> 1) * 32, wn = (w & 1) * 32;
  int bx, by;
  xcd_remap(bx, by);
  const int m0 = bx * 128, n0 = by * 64;
  const int srow = tid >> 3;                  // 0..63
  const int swz8 = ((tid & 7) ^ (srow & 7)) * 8;
  const int r7 = lrow & 7;
  const int nkt = K >> 6;

  const bf16* Ab = A  + (size_t)m0 * K;
  const bf16* Bb = Bt + (size_t)n0 * K;

  f32x4 acc[2][2] = {};

#pragma unroll
  for (int c = 0; c < 2; ++c)
    gload_lds16(Ab + (size_t)(c * 64 + srow) * K + swz8, sA0 + c * 4096 + w * 512);
  gload_lds16(Bb + (size_t)srow * K + swz8, sB0 + w * 512);
  __syncthreads();

  for (int kt = 0; kt < nkt; ++kt) {
    const bf16* pA = (kt & 1) ? sA1 : sA0;
    const bf16* pB = (kt & 1) ? sB1 : sB0;
    bf16* nA = (kt & 1) ? sA0 : sA1;
    bf16* nB = (kt & 1) ? sB0 : sB1;
    const size_t knext = (size_t)(kt + 1) * 64;

    // hoisted staging: full next tile issued BEFORE compute (max cover to the drain)
    if (kt < nkt - 1) {
#pragma unroll
      for (int c = 0; c < 2; ++c)
        gload_lds16(Ab + (size_t)(c * 64 + srow) * K + knext + swz8, nA + c * 4096 + w * 512);
      gload_lds16(Bb + (size_t)srow * K + knext + swz8, nB + w * 512);
    }

#pragma unroll
    for (int kk = 0; kk < 2; ++kk) {
      bf16x8 af[2], bfr[2];
#pragma unroll
      for (int mi = 0; mi < 2; ++mi)
        af[mi] = *(const bf16x8*)&pA[(wm + mi * 16 + lrow) * 64 + ((kk * 4 + lgrp) ^ r7) * 8];
#pragma unroll
      for (int ni = 0; ni < 2; ++ni)
        bfr[ni] = *(const bf16x8*)&pB[(wn + ni * 16 + lrow) * 64 + ((kk * 4 + lgrp) ^ r7) * 8];
      __builtin_amdgcn_s_setprio(1);
#pragma unroll
      for (int mi = 0; mi < 2; ++mi)
#pragma unroll
        for (int ni = 0; ni < 2; ++ni)
          acc[mi][ni] = __builtin_amdgcn_mfma_f32_16x16x32_bf16(af[mi], bfr[ni], acc[mi][ni], 0, 0, 0);
      __builtin_amdgcn_s_setprio(0);
    }
    __syncthreads();
  }

#pragma unroll
  for (int mi = 0; mi < 2; ++mi)
#pragma unroll
    for (int ni = 0; ni < 2; ++ni) {
      const int col = n0 + wn + ni * 16 + lrow;
      const float bv = bias ? bias[col] : 0.f;
#pragma unroll
      for (int j = 0; j < 4; ++j) {
        const int row = m0 + wm + mi * 16 + lgrp * 4 + j;
        C[(size_t)row * N + col] = acc[mi][ni][j] + bv;
      }
    }
}

// ---------------- QKV GEMM, 256x256 tile, hoisted staging + fused rotate ----------------
__global__ __launch_bounds__(512, 2) void k_gemm_qkv256(const bf16* __restrict__ A,
                                                        const bf16* __restrict__ Bt,
                                                        const float* __restrict__ bqkv,
                                                        const float* __restrict__ phases,
                                                        bf16* __restrict__ qb,
                                                        bf16* __restrict__ kb,
                                                        bf16* __restrict__ vb) {
  __shared__ bf16 sA0[16384], sA1[16384];     // 256 x 64 each
  __shared__ bf16 sB0[16384], sB1[16384];
  const int tid = threadIdx.x;
  const int lane = tid & 63, w = tid >> 6;
  const int lrow = lane & 15, lgrp = lane >> 4;
  const int wm = (w >> 2) * 128;
  const int wn = (w & 3) * 64;
  const int m0 = blockIdx.x * 256, n0 = blockIdx.y * 256;
  const int K = 1024;

  const int srow = tid >> 3;
  const int swz8 = (((tid & 7) ^ (srow & 7))) * 8;
  const int r7 = lrow & 7;

  const bf16* Ab = A  + (size_t)m0 * K;
  const bf16* Bb = Bt + (size_t)n0 * K;

  f32x4 acc[8][4] = {};

#pragma unroll
  for (int g = 0; g < 4; ++g) {
    gload_lds16(Ab + (size_t)(g * 64 + srow) * K + swz8, sA0 + g * 4096 + w * 512);
    gload_lds16(Bb + (size_t)(g * 64 + srow) * K + swz8, sB0 + g * 4096 + w * 512);
  }
  __syncthreads();

  for (int kt = 0; kt < 16; ++kt) {
    const bf16* pA = (kt & 1) ? sA1 : sA0;
    const bf16* pB = (kt & 1) ? sB1 : sB0;
    bf16* nA = (kt & 1) ? sA0 : sA1;
    bf16* nB = (kt & 1) ? sB0 : sB1;
    const size_t knext = (size_t)(kt + 1) * 64;

    // hoisted staging: all 8 loads for tile kt+1 issued before any compute
    if (kt < 15) {
#pragma unroll
      for (int g = 0; g < 4; ++g) {
        gload_lds16(Ab + (size_t)(g * 64 + srow) * K + knext + swz8, nA + g * 4096 + w * 512);
        gload_lds16(Bb + (size_t)(g * 64 + srow) * K + knext + swz8, nB + g * 4096 + w * 512);
      }
    }

    bf16x8 bfr[4][2];
#pragma unroll
    for (int ni = 0; ni < 4; ++ni)
#pragma unroll
      for (int kk = 0; kk < 2; ++kk)
        bfr[ni][kk] = *(const bf16x8*)&pB[(wn + ni * 16 + lrow) * 64 + ((kk * 4 + lgrp) ^ r7) * 8];

#pragma unroll
    for (int q = 0; q < 4; ++q) {
      bf16x8 af[2][2];
#pragma unroll
      for (int m2 = 0; m2 < 2; ++m2)
#pragma unroll
        for (int kk = 0; kk < 2; ++kk)
          af[m2][kk] = *(const bf16x8*)&pA[(wm + (q * 2 + m2) * 16 + lrow) * 64 + ((kk * 4 + lgrp) ^ r7) * 8];
      __builtin_amdgcn_s_setprio(1);
#pragma unroll
      for (int m2 = 0; m2 < 2; ++m2)
#pragma unroll
        for (int ni = 0; ni < 4; ++ni)
#pragma unroll
          for (int kk = 0; kk < 2; ++kk)
            acc[q * 2 + m2][ni] =
                __builtin_amdgcn_mfma_f32_16x16x32_bf16(af[m2][kk], bfr[ni][kk], acc[q * 2 + m2][ni], 0, 0, 0);
      __builtin_amdgcn_s_setprio(0);
    }
    __syncthreads();
  }

  // ---- fused epilogue: bias + rotate + pack ----
  const int nw = n0 + wn;
  const int sec = nw >> 10;          // 0=q, 1=k, 2=v
  const int hh = (nw & 1023) >> 6;
  const float b0 = bqkv[nw + lrow];
  const float b1 = bqkv[nw + 16 + lrow];
  const float b2 = bqkv[nw + 32 + lrow];
  const float b3 = bqkv[nw + 48 + lrow];

  if (sec == 2) {
#pragma unroll
    for (int mi = 0; mi < 8; ++mi) {
      const int row0 = m0 + wm + mi * 16 + lgrp * 4;
      const int b = row0 >> 11, l0 = row0 & 2047;
#pragma unroll
      for (int ni = 0; ni < 4; ++ni) {
        const int d = ni * 16 + lrow;
        const float bv = (ni == 0) ? b0 : (ni == 1) ? b1 : (ni == 2) ? b2 : b3;
        bf16x4 pv;
#pragma unroll
        for (int j = 0; j < 4; ++j) pv[j] = f2bf(acc[mi][ni][j] + bv);
        *(bf16x4*)&vb[(((size_t)(b * 16 + hh)) * 64 + d) * 2048 + l0] = pv;
      }
    }
  } else {
    bf16* qk = sec ? kb : qb;
    const float qs = sec ? 1.0f : QSCALE;
#pragma unroll
    for (int mi = 0; mi < 8; ++mi) {
#pragma unroll
      for (int j = 0; j < 4; ++j) {
        const int row = m0 + wm + mi * 16 + lgrp * 4 + j;
        const int b = row >> 11, l = row & 2047;
        const float ph1 = phases[(size_t)row * 512 + hh * 32 + lrow];
        const float ph2 = phases[(size_t)row * 512 + hh * 32 + 16 + lrow];
        float s1, c1, s2, c2;
        __sincosf(ph1, &s1, &c1);
        __sincosf(ph2, &s2, &c2);
        const float t0 = acc[mi][0][j] + b0;
        const float t1 = acc[mi][1][j] + b1;
        const float t2 = acc[mi][2][j] + b2;
        const float t3 = acc[mi][3][j] + b3;
        bf16* base = qk + (((size_t)(b * 16 + hh)) * 2048 + l) * 64;
        base[lrow]      = f2bf((t0 * c1 - t2 * s1) * qs);
        base[16 + lrow] = f2bf((t1 * c2 - t3 * s2) * qs);
        base[32 + lrow] = f2bf((t0 * s1 + t2 * c1) * qs);
        base[48 + lrow] = f2bf((t1 * s2 + t3 * c2) * qs);
      }
    }
  }
}

// ---------------- flash attention v9b: hoisted staging variant of v9 ----------------
__global__ __launch_bounds__(256, 4) void k_flash_attn9(const bf16* __restrict__ qb,
                                                        const bf16* __restrict__ kb,
                                                        const bf16* __restrict__ vb,
                                                        bf16* __restrict__ attnout) {
  const int tid = threadIdx.x, lane = tid & 63, w = tid >> 6;
  const int ql = lane & 31, hi = lane >> 5;
  const int tsel = w >> 1;
  const int qh = w & 1;
  const int fid = blockIdx.x;
  const int nid = (fid & 7) * 128 + (fid >> 3);
  const int qblk = nid & 31, h = (nid >> 5) & 15, b = nid >> 9;
  const size_t bh = (size_t)b * 16 + h;
  const bf16* Kp = kb + bh * 2048 * 64;
  const bf16* Vp = vb + bh * 64 * 2048;

  __shared__ __align__(16) char smem[40960];
  bf16* sKb[3] = { (bf16*)smem, (bf16*)(smem + 8192), (bf16*)(smem + 16384) };
  bf16* sVb[2] = { (bf16*)(smem + 24576), (bf16*)(smem + 32768) };

  const bf16* Qp = qb + (bh * 2048 + (size_t)qblk * 64 + qh * 32 + ql) * 64;
  bf16x8 qf[4];
#pragma unroll
  for (int c = 0; c < 4; ++c) qf[c] = *(const bf16x8*)(Qp + c * 16 + hi * 8);

  const int srow = tid >> 3;
  const int swz = (tid & 7) ^ (srow & 7);
  const int jk0 = (0 * 2 + hi) ^ (ql & 7), jk1 = (1 * 2 + hi) ^ (ql & 7);
  const int jk2 = (2 * 2 + hi) ^ (ql & 7), jk3 = (3 * 2 + hi) ^ (ql & 7);
  const int jv0 = (tsel * 4 + 0 + hi) ^ (ql & 7);
  const int jv1 = (tsel * 4 + 2 + hi) ^ (ql & 7);
  const int krow = (tsel * 32 + ql) * 64;

  f32x16 o0 = {}, o1 = {};
  float lsum = 0.f;
  u32 pcu[8];
  bf16x8 vfr[4];
  bf16x8 kfn[4];

#define STAGE_K(PTR, KV0)                                                                    \
  do {                                                                                       \
    gload_lds16(Kp + (size_t)((KV0) + srow) * 64 + swz * 8,      (PTR) + w * 512);           \
    gload_lds16(Kp + (size_t)((KV0) + srow + 32) * 64 + swz * 8, (PTR) + 2048 + w * 512);    \
  } while (0)
#define STAGE_V(PTR, KV0)                                                                    \
  do {                                                                                       \
    gload_lds16(Vp + (size_t)srow * 2048 + (KV0) + swz * 8,        (PTR) + w * 512);         \
    gload_lds16(Vp + (size_t)(srow + 32) * 2048 + (KV0) + swz * 8, (PTR) + 2048 + w * 512);  \
  } while (0)

#define KF_PREFETCH(PTR)                                       \
  do {                                                         \
    kfn[0] = *(const bf16x8*)&(PTR)[krow + jk0 * 8];           \
    kfn[1] = *(const bf16x8*)&(PTR)[krow + jk1 * 8];           \
    kfn[2] = *(const bf16x8*)&(PTR)[krow + jk2 * 8];           \
    kfn[3] = *(const bf16x8*)&(PTR)[krow + jk3 * 8];           \
  } while (0)

#define SM_PACK(VPTR)                                                               \
  do {                                                                              \
    _Pragma("unroll")                                                               \
    for (int j2 = 0; j2 < 16; ++j2) {                                               \
      float pv = EXP2(st0[j2]);                                                     \
      st0[j2] = pv; lsum += pv;                                                     \
    }                                                                               \
    {                                                                               \
      u32 a0 = cvtpk_bf16(st0[0], st0[1]),  a1 = cvtpk_bf16(st0[2], st0[3]);        \
      u32 a2 = cvtpk_bf16(st0[4], st0[5]),  a3 = cvtpk_bf16(st0[6], st0[7]);        \
      perm32swap(a0, a2); perm32swap(a1, a3);                                       \
      pcu[0] = a0; pcu[1] = a1; pcu[2] = a2; pcu[3] = a3;                           \
      u32 b0 = cvtpk_bf16(st0[8], st0[9]),  b1 = cvtpk_bf16(st0[10], st0[11]);      \
      u32 b2 = cvtpk_bf16(st0[12], st0[13]), b3 = cvtpk_bf16(st0[14], st0[15]);     \
      perm32swap(b0, b2); perm32swap(b1, b3);                                       \
      pcu[4] = b0; pcu[5] = b1; pcu[6] = b2; pcu[7] = b3;                           \
    }                                                                               \
    vfr[0] = *(const bf16x8*)&(VPTR)[ql * 64 + jv0 * 8];                            \
    vfr[1] = *(const bf16x8*)&(VPTR)[(32 + ql) * 64 + jv0 * 8];                     \
    vfr[2] = *(const bf16x8*)&(VPTR)[ql * 64 + jv1 * 8];                            \
    vfr[3] = *(const bf16x8*)&(VPTR)[(32 + ql) * 64 + jv1 * 8];                     \
  } while (0)

#define PV_PREV()                                                                   \
  do {                                                                              \
    union { u32 u[4]; bf16x8 v; } cA, cB;                                           \
    cA.u[0] = pcu[0]; cA.u[1] = pcu[1]; cA.u[2] = pcu[2]; cA.u[3] = pcu[3];         \
    cB.u[0] = pcu[4]; cB.u[1] = pcu[5]; cB.u[2] = pcu[6]; cB.u[3] = pcu[7];         \
    __builtin_amdgcn_s_setprio(1);                                                  \
    o0 = __builtin_amdgcn_mfma_f32_32x32x16_bf16(vfr[0], cA.v, o0, 0, 0, 0);        \
    o1 = __builtin_amdgcn_mfma_f32_32x32x16_bf16(vfr[1], cA.v, o1, 0, 0, 0);        \
    o0 = __builtin_amdgcn_mfma_f32_32x32x16_bf16(vfr[2], cB.v, o0, 0, 0, 0);        \
    o1 = __builtin_amdgcn_mfma_f32_32x32x16_bf16(vfr[3], cB.v, o1, 0, 0, 0);        \
    __builtin_amdgcn_s_setprio(0);                                                  \
  } while (0)

  bf16 *ka = sKb[0], *kbuf = sKb[1], *kc = sKb[2];
  bf16 *va = sVb[0], *vbuf = sVb[1];

  STAGE_K(ka, 0);
  STAGE_K(kbuf, 64);
  STAGE_V(va, 0);
  __syncthreads();

  // ---- iter 0: staging at top; QK(0) from LDS; SM(0) ----
  {
    STAGE_K(kc, 128);                  // K(2)
    STAGE_V(vbuf, 64);                 // V(1)
    f32x16 st0 = {};
    bf16x8 kf0 = *(const bf16x8*)&ka[krow + jk0 * 8];
    bf16x8 kf1 = *(const bf16x8*)&ka[krow + jk1 * 8];
    bf16x8 kf2 = *(const bf16x8*)&ka[krow + jk2 * 8];
    bf16x8 kf3 = *(const bf16x8*)&ka[krow + jk3 * 8];
    __builtin_amdgcn_s_setprio(1);
    st0 = __builtin_amdgcn_mfma_f32_32x32x16_bf16(kf0, qf[0], st0, 0, 0, 0);
    st0 = __builtin_amdgcn_mfma_f32_32x32x16_bf16(kf1, qf[1], st0, 0, 0, 0);
    st0 = __builtin_amdgcn_mfma_f32_32x32x16_bf16(kf2, qf[2], st0, 0, 0, 0);
    st0 = __builtin_amdgcn_mfma_f32_32x32x16_bf16(kf3, qf[3], st0, 0, 0, 0);
    __builtin_amdgcn_s_setprio(0);
    KF_PREFETCH(kbuf);                 // K(1) drained at prologue barrier
    SM_PACK(va);                       // V(0)
    __syncthreads();
    bf16* tmp = ka; ka = kbuf; kbuf = kc; kc = tmp;
    bf16* tv = va; va = vbuf; vbuf = tv;
  }

  // ---- steady state: staging at top, then QK -> PV(prev) -> kf prefetch -> SM ----
  for (int t = 1; t < 32; ++t) {
    if (t < 31) {
      STAGE_V(vbuf, (t + 1) * 64);
      if (t < 30) STAGE_K(kc, (t + 2) * 64);
    }
    f32x16 st0 = {};
    __builtin_amdgcn_s_setprio(1);
    st0 = __builtin_amdgcn_mfma_f32_32x32x16_bf16(kfn[0], qf[0], st0, 0, 0, 0);
    st0 = __builtin_amdgcn_mfma_f32_32x32x16_bf16(kfn[1], qf[1], st0, 0, 0, 0);
    st0 = __builtin_amdgcn_mfma_f32_32x32x16_bf16(kfn[2], qf[2], st0, 0, 0, 0);
    st0 = __builtin_amdgcn_mfma_f32_32x32x16_bf16(kfn[3], qf[3], st0, 0, 0, 0);
    __builtin_amdgcn_s_setprio(0);
    PV_PREV();
    if (t < 31) KF_PREFETCH(kbuf);
    SM_PACK(va);
    __syncthreads();
    bf16* tmp = ka; ka = kbuf; kbuf = kc; kc = tmp;
    bf16* tv = va; va = vbuf; vbuf = tv;
  }

  PV_PREV();

  // ---- combine partials across kv halves ----
  float* cb = (float*)smem;
  if (w >= 2) {
    const int idx = ((w - 2) * 64 + lane) * 34;
#pragma unroll
    for (int i = 0; i < 16; ++i) cb[idx + i] = o0[i];
#pragma unroll
    for (int i = 0; i < 16; ++i) cb[idx + 16 + i] = o1[i];
    cb[idx + 32] = lsum;
  }
  __syncthreads();
  if (w < 2) {
    const int idx = (w * 64 + lane) * 34;
#pragma unroll
    for (int i = 0; i < 16; ++i) o0[i] += cb[idx + i];
#pragma unroll
    for (int i = 0; i < 16; ++i) o1[i] += cb[idx + 16 + i];
    lsum += cb[idx + 32];
    lsum += __shfl_xor(lsum, 32);

    const float inv = 1.f / lsum;
    const int qrow = qblk * 64 + qh * 32 + ql;
    bf16* outp = attnout + ((size_t)b * 2048 + qrow) * 1024 + h * 64;
#pragma unroll
    for (int j2 = 0; j2 < 4; ++j2) {
      bf16x4 ov;
#pragma unroll
      for (int jj = 0; jj < 4; ++jj) ov[jj] = f2bf(o0[j2 * 4 + jj] * inv);
      *(bf16x4*)(outp + j2 * 8 + hi * 4) = ov;
#pragma unroll
      for (int jj = 0; jj < 4; ++jj) ov[jj] = f2bf(o1[j2 * 4 + jj] * inv);
      *(bf16x4*)(outp + 32 + j2 * 8 + hi * 4) = ov;
    }
  }
#undef STAGE_K
#undef STAGE_V
#undef KF_PREFETCH
#undef SM_PACK
#undef PV_PREV
}

// ---------------- launch ----------------
extern "C" void kernel_launch(void* const* d_in, const int* in_sizes, int n_in,
                              void* d_out, int out_size, void* d_ws, size_t ws_size,
                              hipStream_t stream) {
  (void)in_sizes; (void)n_in; (void)out_size; (void)ws_size;
  const float* x    = (const float*)d_in[0];
  const float* p    = (const float*)d_in[1];
  const float* Wqkv = (const float*)d_in[2];
  const float* bqkv = (const float*)d_in[3];
  const float* Wout = (const float*)d_in[4];
  const float* bout = (const float*)d_in[5];
  const float* proj = (const float*)d_in[6];
  float* out = (float*)d_out;

  char* ws = (char*)d_ws;
  size_t off = 0;
  bf16* xb     = (bf16*)(ws + off); off += (size_t)4096 * 1024 * 2;
  bf16* pb     = (bf16*)(ws + off); off += (size_t)4096 * 1024 * 2;
  bf16* WqkvT  = (bf16*)(ws + off); off += (size_t)3072 * 1024 * 2;
  bf16* projT  = (bf16*)(ws + off); off += (size_t)512  * 1024 * 2;
  bf16* WoutT  = (bf16*)(ws + off); off += (size_t)1024 * 1024 * 2;
  float* phases= (float*)(ws + off); off += (size_t)4096 * 512 * 4;
  bf16* qb     = (bf16*)(ws + off); off += (size_t)4096 * 1024 * 2;
  bf16* kb     = (bf16*)(ws + off); off += (size_t)4096 * 1024 * 2;
  bf16* vb     = (bf16*)(ws + off); off += (size_t)4096 * 1024 * 2;
  bf16* attnb  = (bf16*)(ws + off); off += (size_t)4096 * 1024 * 2;

  k_prep<<<9344, 256, 0, stream>>>(x, xb, p, pb, Wqkv, WqkvT, proj, projT, Wout, WoutT);

  k_gemm128x64<<<dim3(32, 8), 512, 0, stream>>>(pb, projT, nullptr, phases, 4096, 512, 1024);
  k_gemm_qkv256<<<dim3(16, 12), 512, 0, stream>>>(xb, WqkvT, bqkv, phases, qb, kb, vb);

  k_flash_attn9<<<1024, 256, 0, stream>>>(qb, kb, vb, attnb);

  k_gemm128x64<<<dim3(32, 16), 512, 0, stream>>>(attnb, WoutT, bout, out, 4096, 1024, 1024);
}

// Round 18
// 122.432 us; speedup vs baseline: 1.0275x; 1.0275x over previous
//
#include <hip/hip_runtime.h>

// FlashCRA on MI355X — round 18:
//  - attention v11: QBLK=128, 8-wave blocks (512 thr). Waves {0-3}/{4-7} serve q-halves
//    with v9's proven roles; K/V staged ONCE per 128 q-rows (staging traffic halves).
//    Grid 512 = 2 blocks/CU x 8 waves = 16 waves/CU (same occupancy as v9).
//  - everything else = round 17 (passing, 125.8us).

typedef __bf16 bf16;
typedef __bf16 bf16x8 __attribute__((ext_vector_type(8)));
typedef __bf16 bf16x4 __attribute__((ext_vector_type(4)));
typedef float f32x4 __attribute__((ext_vector_type(4)));
typedef float f32x16 __attribute__((ext_vector_type(16)));
typedef unsigned int u32;

__device__ __forceinline__ bf16 f2bf(float f) {
  unsigned u = __builtin_bit_cast(unsigned, f);
  u += 0x7FFFu + ((u >> 16) & 1u);            // RNE, inputs finite
  unsigned short h = (unsigned short)(u >> 16);
  return __builtin_bit_cast(bf16, h);
}

__device__ __forceinline__ void gload_lds16(const bf16* g, bf16* l) {
  __builtin_amdgcn_global_load_lds((const __attribute__((address_space(1))) u32*)(const void*)g,
                                   (__attribute__((address_space(3))) u32*)(void*)l, 16, 0, 0);
}

__device__ __forceinline__ u32 cvtpk_bf16(float lo, float hi) {
  u32 r;
  asm("v_cvt_pk_bf16_f32 %0, %1, %2" : "=v"(r) : "v"(lo), "v"(hi));
  return r;
}
__device__ __forceinline__ void perm32swap(u32& a, u32& b) {
  asm("v_permlane32_swap_b32 %0, %1" : "+v"(a), "+v"(b));
}

#if __has_builtin(__builtin_amdgcn_exp2f)
#define EXP2(x) __builtin_amdgcn_exp2f(x)
#else
#define EXP2(x) exp2f(x)
#endif

// SCALE * log2(e), folded into Q at pack time
#define QSCALE 0.18033688f

// XCD-chunked bijective remap (requires gridDim.x*gridDim.y % 8 == 0)
__device__ __forceinline__ void xcd_remap(int& bx, int& by) {
  const int nx = gridDim.x;
  const int nwg = nx * gridDim.y;
  const int lin = blockIdx.y * nx + blockIdx.x;
  const int chunk = nwg >> 3;
  const int nid = (lin & 7) * chunk + (lin >> 3);
  bx = nid % nx;
  by = nid / nx;
}

// ---------------- merged prep: x,p fp32->bf16 + 3 weight transposes ----------------
__global__ __launch_bounds__(256) void k_prep(const float* __restrict__ x, bf16* __restrict__ xb,
                                              const float* __restrict__ p, bf16* __restrict__ pb,
                                              const float* __restrict__ W1, bf16* __restrict__ O1,
                                              const float* __restrict__ W2, bf16* __restrict__ O2,
                                              const float* __restrict__ W3, bf16* __restrict__ O3) {
  const int gb = blockIdx.x;
  if (gb < 8192) {
    int i = gb * 256 + threadIdx.x;
    const float* in = x; bf16* out = xb;
    if (i >= 1048576) { in = p; out = pb; i -= 1048576; }
    const float4 v = ((const float4*)in)[i];
    bf16x4 o;
    o[0] = f2bf(v.x); o[1] = f2bf(v.y); o[2] = f2bf(v.z); o[3] = f2bf(v.w);
    *(bf16x4*)(out + (size_t)i * 4) = o;
    return;
  }
  __shared__ float t[64][65];
  const int lin = gb - 8192;
  int bx = lin % 72;
  const int by = lin / 72;
  const float* in; bf16* out; int C;
  if (bx < 48)      { in = W1; out = O1; C = 3072; }
  else if (bx < 56) { in = W2; out = O2; C = 512;  bx -= 48; }
  else              { in = W3; out = O3; C = 1024; bx -= 56; }
  const int R = 1024;
  const int c0 = bx * 64, r0 = by * 64;
  for (int e = threadIdx.x; e < 4096; e += 256) {
    int r = e >> 6, c = e & 63;
    t[r][c] = in[(size_t)(r0 + r) * C + c0 + c];
  }
  __syncthreads();
  for (int e = threadIdx.x; e < 4096; e += 256) {
    int c = e >> 6, r = e & 63;
    out[(size_t)(c0 + c) * R + r0 + r] = f2bf(t[r][c]);
  }
}

// ---------------- C[M][N] = A @ Bt^T + bias — 128x64 tile, 8 waves, 2 blocks/CU ----------------
__global__ __launch_bounds__(512, 4) void k_gemm128x64(const bf16* __restrict__ A,
                                                       const bf16* __restrict__ Bt,
                                                       const float* __restrict__ bias,
                                                       float* __restrict__ C,
                                                       int M, int N, int K) {
  __shared__ bf16 sA0[8192], sA1[8192];       // 128 x 64
  __shared__ bf16 sB0[4096], sB1[4096];       // 64 x 64
  const int tid = threadIdx.x;
  const int lane = tid & 63, w = tid >> 6;
  const int lrow = lane & 15, lgrp = lane >> 4;
  const int wm = (w >> 1) * 32, wn = (w & 1) * 32;
  int bx, by;
  xcd_remap(bx, by);
  const int m0 = bx * 128, n0 = by * 64;
  const int srow = tid >> 3;                  // 0..63
  const int swz8 = ((tid & 7) ^ (srow & 7)) * 8;
  const int r7 = lrow & 7;
  const int nkt = K >> 6;

  const bf16* Ab = A  + (size_t)m0 * K;
  const bf16* Bb = Bt + (size_t)n0 * K;

  f32x4 acc[2][2] = {};

#pragma unroll
  for (int c = 0; c < 2; ++c)
    gload_lds16(Ab + (size_t)(c * 64 + srow) * K + swz8, sA0 + c * 4096 + w * 512);
  gload_lds16(Bb + (size_t)srow * K + swz8, sB0 + w * 512);
  __syncthreads();

  for (int kt = 0; kt < nkt; ++kt) {
    const bf16* pA = (kt & 1) ? sA1 : sA0;
    const bf16* pB = (kt & 1) ? sB1 : sB0;
    bf16* nA = (kt & 1) ? sA0 : sA1;
    bf16* nB = (kt & 1) ? sB0 : sB1;
    const size_t knext = (size_t)(kt + 1) * 64;

    if (kt < nkt - 1) {
#pragma unroll
      for (int c = 0; c < 2; ++c)
        gload_lds16(Ab + (size_t)(c * 64 + srow) * K + knext + swz8, nA + c * 4096 + w * 512);
      gload_lds16(Bb + (size_t)srow * K + knext + swz8, nB + w * 512);
    }

#pragma unroll
    for (int kk = 0; kk < 2; ++kk) {
      bf16x8 af[2], bfr[2];
#pragma unroll
      for (int mi = 0; mi < 2; ++mi)
        af[mi] = *(const bf16x8*)&pA[(wm + mi * 16 + lrow) * 64 + ((kk * 4 + lgrp) ^ r7) * 8];
#pragma unroll
      for (int ni = 0; ni < 2; ++ni)
        bfr[ni] = *(const bf16x8*)&pB[(wn + ni * 16 + lrow) * 64 + ((kk * 4 + lgrp) ^ r7) * 8];
      __builtin_amdgcn_s_setprio(1);
#pragma unroll
      for (int mi = 0; mi < 2; ++mi)
#pragma unroll
        for (int ni = 0; ni < 2; ++ni)
          acc[mi][ni] = __builtin_amdgcn_mfma_f32_16x16x32_bf16(af[mi], bfr[ni], acc[mi][ni], 0, 0, 0);
      __builtin_amdgcn_s_setprio(0);
    }
    __syncthreads();
  }

#pragma unroll
  for (int mi = 0; mi < 2; ++mi)
#pragma unroll
    for (int ni = 0; ni < 2; ++ni) {
      const int col = n0 + wn + ni * 16 + lrow;
      const float bv = bias ? bias[col] : 0.f;
#pragma unroll
      for (int j = 0; j < 4; ++j) {
        const int row = m0 + wm + mi * 16 + lgrp * 4 + j;
        C[(size_t)row * N + col] = acc[mi][ni][j] + bv;
      }
    }
}

// ---------------- QKV GEMM, 256x256 tile, hoisted staging + fused rotate ----------------
__global__ __launch_bounds__(512, 2) void k_gemm_qkv256(const bf16* __restrict__ A,
                                                        const bf16* __restrict__ Bt,
                                                        const float* __restrict__ bqkv,
                                                        const float* __restrict__ phases,
                                                        bf16* __restrict__ qb,
                                                        bf16* __restrict__ kb,
                                                        bf16* __restrict__ vb) {
  __shared__ bf16 sA0[16384], sA1[16384];     // 256 x 64 each
  __shared__ bf16 sB0[16384], sB1[16384];
  const int tid = threadIdx.x;
  const int lane = tid & 63, w = tid >> 6;
  const int lrow = lane & 15, lgrp = lane >> 4;
  const int wm = (w >> 2) * 128;
  const int wn = (w & 3) * 64;
  const int m0 = blockIdx.x * 256, n0 = blockIdx.y * 256;
  const int K = 1024;

  const int srow = tid >> 3;
  const int swz8 = (((tid & 7) ^ (srow & 7))) * 8;
  const int r7 = lrow & 7;

  const bf16* Ab = A  + (size_t)m0 * K;
  const bf16* Bb = Bt + (size_t)n0 * K;

  f32x4 acc[8][4] = {};

#pragma unroll
  for (int g = 0; g < 4; ++g) {
    gload_lds16(Ab + (size_t)(g * 64 + srow) * K + swz8, sA0 + g * 4096 + w * 512);
    gload_lds16(Bb + (size_t)(g * 64 + srow) * K + swz8, sB0 + g * 4096 + w * 512);
  }
  __syncthreads();

  for (int kt = 0; kt < 16; ++kt) {
    const bf16* pA = (kt & 1) ? sA1 : sA0;
    const bf16* pB = (kt & 1) ? sB1 : sB0;
    bf16* nA = (kt & 1) ? sA0 : sA1;
    bf16* nB = (kt & 1) ? sB0 : sB1;
    const size_t knext = (size_t)(kt + 1) * 64;

    if (kt < 15) {
#pragma unroll
      for (int g = 0; g < 4; ++g) {
        gload_lds16(Ab + (size_t)(g * 64 + srow) * K + knext + swz8, nA + g * 4096 + w * 512);
        gload_lds16(Bb + (size_t)(g * 64 + srow) * K + knext + swz8, nB + g * 4096 + w * 512);
      }
    }

    bf16x8 bfr[4][2];
#pragma unroll
    for (int ni = 0; ni < 4; ++ni)
#pragma unroll
      for (int kk = 0; kk < 2; ++kk)
        bfr[ni][kk] = *(const bf16x8*)&pB[(wn + ni * 16 + lrow) * 64 + ((kk * 4 + lgrp) ^ r7) * 8];

#pragma unroll
    for (int q = 0; q < 4; ++q) {
      bf16x8 af[2][2];
#pragma unroll
      for (int m2 = 0; m2 < 2; ++m2)
#pragma unroll
        for (int kk = 0; kk < 2; ++kk)
          af[m2][kk] = *(const bf16x8*)&pA[(wm + (q * 2 + m2) * 16 + lrow) * 64 + ((kk * 4 + lgrp) ^ r7) * 8];
      __builtin_amdgcn_s_setprio(1);
#pragma unroll
      for (int m2 = 0; m2 < 2; ++m2)
#pragma unroll
        for (int ni = 0; ni < 4; ++ni)
#pragma unroll
          for (int kk = 0; kk < 2; ++kk)
            acc[q * 2 + m2][ni] =
                __builtin_amdgcn_mfma_f32_16x16x32_bf16(af[m2][kk], bfr[ni][kk], acc[q * 2 + m2][ni], 0, 0, 0);
      __builtin_amdgcn_s_setprio(0);
    }
    __syncthreads();
  }

  // ---- fused epilogue: bias + rotate + pack ----
  const int nw = n0 + wn;
  const int sec = nw >> 10;          // 0=q, 1=k, 2=v
  const int hh = (nw & 1023) >> 6;
  const float b0 = bqkv[nw + lrow];
  const float b1 = bqkv[nw + 16 + lrow];
  const float b2 = bqkv[nw + 32 + lrow];
  const float b3 = bqkv[nw + 48 + lrow];

  if (sec == 2) {
#pragma unroll
    for (int mi = 0; mi < 8; ++mi) {
      const int row0 = m0 + wm + mi * 16 + lgrp * 4;
      const int b = row0 >> 11, l0 = row0 & 2047;
#pragma unroll
      for (int ni = 0; ni < 4; ++ni) {
        const int d = ni * 16 + lrow;
        const float bv = (ni == 0) ? b0 : (ni == 1) ? b1 : (ni == 2) ? b2 : b3;
        bf16x4 pv;
#pragma unroll
        for (int j = 0; j < 4; ++j) pv[j] = f2bf(acc[mi][ni][j] + bv);
        *(bf16x4*)&vb[(((size_t)(b * 16 + hh)) * 64 + d) * 2048 + l0] = pv;
      }
    }
  } else {
    bf16* qk = sec ? kb : qb;
    const float qs = sec ? 1.0f : QSCALE;
#pragma unroll
    for (int mi = 0; mi < 8; ++mi) {
#pragma unroll
      for (int j = 0; j < 4; ++j) {
        const int row = m0 + wm + mi * 16 + lgrp * 4 + j;
        const int b = row >> 11, l = row & 2047;
        const float ph1 = phases[(size_t)row * 512 + hh * 32 + lrow];
        const float ph2 = phases[(size_t)row * 512 + hh * 32 + 16 + lrow];
        float s1, c1, s2, c2;
        __sincosf(ph1, &s1, &c1);
        __sincosf(ph2, &s2, &c2);
        const float t0 = acc[mi][0][j] + b0;
        const float t1 = acc[mi][1][j] + b1;
        const float t2 = acc[mi][2][j] + b2;
        const float t3 = acc[mi][3][j] + b3;
        bf16* base = qk + (((size_t)(b * 16 + hh)) * 2048 + l) * 64;
        base[lrow]      = f2bf((t0 * c1 - t2 * s1) * qs);
        base[16 + lrow] = f2bf((t1 * c2 - t3 * s2) * qs);
        base[32 + lrow] = f2bf((t0 * s1 + t2 * c1) * qs);
        base[48 + lrow] = f2bf((t1 * s2 + t3 * c2) * qs);
      }
    }
  }
}

// ---------------- flash attention v11: QBLK=128, 8 waves share one staged pipeline ----------------
// Waves: qgrp = w>>2 (q 64-block), tsel = (w>>1)&1 (kv half), qh = w&1 (q 32-half).
// Staging: 512 threads cover a 64x64 tile with ONE gload_lds each (rows tid>>3).
// Inner loop per wave identical to proven v9 (kf prefetch, SM_PACK, PV_PREV).
__global__ __launch_bounds__(512, 4) void k_flash_attn11(const bf16* __restrict__ qb,
                                                         const bf16* __restrict__ kb,
                                                         const bf16* __restrict__ vb,
                                                         bf16* __restrict__ attnout) {
  const int tid = threadIdx.x, lane = tid & 63, w = tid >> 6;
  const int ql = lane & 31, hi = lane >> 5;
  const int qgrp = w >> 2;
  const int tsel = (w >> 1) & 1;
  const int qh = w & 1;
  // XCD-aware swizzle over 512 blocks: 64 consecutive nids per XCD
  const int fid = blockIdx.x;
  const int nid = (fid & 7) * 64 + (fid >> 3);
  const int qblk = nid & 15, h = (nid >> 4) & 15, b = nid >> 8;
  const size_t bh = (size_t)b * 16 + h;
  const bf16* Kp = kb + bh * 2048 * 64;
  const bf16* Vp = vb + bh * 64 * 2048;

  __shared__ __align__(16) char smem[40960];
  bf16* sKb[3] = { (bf16*)smem, (bf16*)(smem + 8192), (bf16*)(smem + 16384) };
  bf16* sVb[2] = { (bf16*)(smem + 24576), (bf16*)(smem + 32768) };

  const bf16* Qp = qb + (bh * 2048 + (size_t)qblk * 128 + qgrp * 64 + qh * 32 + ql) * 64;
  bf16x8 qf[4];
#pragma unroll
  for (int c = 0; c < 4; ++c) qf[c] = *(const bf16x8*)(Qp + c * 16 + hi * 8);

  const int srow = tid >> 3;                   // 0..63 (one row per 8 lanes)
  const int swz = (tid & 7) ^ (srow & 7);
  const int jk0 = (0 * 2 + hi) ^ (ql & 7), jk1 = (1 * 2 + hi) ^ (ql & 7);
  const int jk2 = (2 * 2 + hi) ^ (ql & 7), jk3 = (3 * 2 + hi) ^ (ql & 7);
  const int jv0 = (tsel * 4 + 0 + hi) ^ (ql & 7);
  const int jv1 = (tsel * 4 + 2 + hi) ^ (ql & 7);
  const int krow = (tsel * 32 + ql) * 64;

  f32x16 o0 = {}, o1 = {};
  float lsum = 0.f;
  u32 pcu[8];
  bf16x8 vfr[4];
  bf16x8 kfn[4];

// one gload per thread covers the whole 64x64 tile (8 waves x 512 elems)
#define STAGE_K(PTR, KV0)                                                               \
  gload_lds16(Kp + (size_t)((KV0) + srow) * 64 + swz * 8, (PTR) + w * 512)
#define STAGE_V(PTR, KV0)                                                               \
  gload_lds16(Vp + (size_t)srow * 2048 + (KV0) + swz * 8, (PTR) + w * 512)

#define KF_PREFETCH(PTR)                                       \
  do {                                                         \
    kfn[0] = *(const bf16x8*)&(PTR)[krow + jk0 * 8];           \
    kfn[1] = *(const bf16x8*)&(PTR)[krow + jk1 * 8];           \
    kfn[2] = *(const bf16x8*)&(PTR)[krow + jk2 * 8];           \
    kfn[3] = *(const bf16x8*)&(PTR)[krow + jk3 * 8];           \
  } while (0)

#define SM_PACK(VPTR)                                                               \
  do {                                                                              \
    _Pragma("unroll")                                                               \
    for (int j2 = 0; j2 < 16; ++j2) {                                               \
      float pv = EXP2(st0[j2]);                                                     \
      st0[j2] = pv; lsum += pv;                                                     \
    }                                                                               \
    {                                                                               \
      u32 a0 = cvtpk_bf16(st0[0], st0[1]),  a1 = cvtpk_bf16(st0[2], st0[3]);        \
      u32 a2 = cvtpk_bf16(st0[4], st0[5]),  a3 = cvtpk_bf16(st0[6], st0[7]);        \
      perm32swap(a0, a2); perm32swap(a1, a3);                                       \
      pcu[0] = a0; pcu[1] = a1; pcu[2] = a2; pcu[3] = a3;                           \
      u32 b0 = cvtpk_bf16(st0[8], st0[9]),  b1 = cvtpk_bf16(st0[10], st0[11]);      \
      u32 b2 = cvtpk_bf16(st0[12], st0[13]), b3 = cvtpk_bf16(st0[14], st0[15]);     \
      perm32swap(b0, b2); perm32swap(b1, b3);                                       \
      pcu[4] = b0; pcu[5] = b1; pcu[6] = b2; pcu[7] = b3;                           \
    }                                                                               \
    vfr[0] = *(const bf16x8*)&(VPTR)[ql * 64 + jv0 * 8];                            \
    vfr[1] = *(const bf16x8*)&(VPTR)[(32 + ql) * 64 + jv0 * 8];                     \
    vfr[2] = *(const bf16x8*)&(VPTR)[ql * 64 + jv1 * 8];                            \
    vfr[3] = *(const bf16x8*)&(VPTR)[(32 + ql) * 64 + jv1 * 8];                     \
  } while (0)

#define PV_PREV()                                                                   \
  do {                                                                              \
    union { u32 u[4]; bf16x8 v; } cA, cB;                                           \
    cA.u[0] = pcu[0]; cA.u[1] = pcu[1]; cA.u[2] = pcu[2]; cA.u[3] = pcu[3];         \
    cB.u[0] = pcu[4]; cB.u[1] = pcu[5]; cB.u[2] = pcu[6]; cB.u[3] = pcu[7];         \
    __builtin_amdgcn_s_setprio(1);                                                  \
    o0 = __builtin_amdgcn_mfma_f32_32x32x16_bf16(vfr[0], cA.v, o0, 0, 0, 0);        \
    o1 = __builtin_amdgcn_mfma_f32_32x32x16_bf16(vfr[1], cA.v, o1, 0, 0, 0);        \
    o0 = __builtin_amdgcn_mfma_f32_32x32x16_bf16(vfr[2], cB.v, o0, 0, 0, 0);        \
    o1 = __builtin_amdgcn_mfma_f32_32x32x16_bf16(vfr[3], cB.v, o1, 0, 0, 0);        \
    __builtin_amdgcn_s_setprio(0);                                                  \
  } while (0)

  bf16 *ka = sKb[0], *kbuf = sKb[1], *kc = sKb[2];
  bf16 *va = sVb[0], *vbuf = sVb[1];

  STAGE_K(ka, 0);
  STAGE_K(kbuf, 64);
  STAGE_V(va, 0);
  __syncthreads();

  // ---- iter 0 ----
  {
    STAGE_K(kc, 128);
    STAGE_V(vbuf, 64);
    f32x16 st0 = {};
    bf16x8 kf0 = *(const bf16x8*)&ka[krow + jk0 * 8];
    bf16x8 kf1 = *(const bf16x8*)&ka[krow + jk1 * 8];
    bf16x8 kf2 = *(const bf16x8*)&ka[krow + jk2 * 8];
    bf16x8 kf3 = *(const bf16x8*)&ka[krow + jk3 * 8];
    __builtin_amdgcn_s_setprio(1);
    st0 = __builtin_amdgcn_mfma_f32_32x32x16_bf16(kf0, qf[0], st0, 0, 0, 0);
    st0 = __builtin_amdgcn_mfma_f32_32x32x16_bf16(kf1, qf[1], st0, 0, 0, 0);
    st0 = __builtin_amdgcn_mfma_f32_32x32x16_bf16(kf2, qf[2], st0, 0, 0, 0);
    st0 = __builtin_amdgcn_mfma_f32_32x32x16_bf16(kf3, qf[3], st0, 0, 0, 0);
    __builtin_amdgcn_s_setprio(0);
    KF_PREFETCH(kbuf);
    SM_PACK(va);
    __syncthreads();
    bf16* tmp = ka; ka = kbuf; kbuf = kc; kc = tmp;
    bf16* tv = va; va = vbuf; vbuf = tv;
  }

  // ---- steady state ----
  for (int t = 1; t < 32; ++t) {
    if (t < 31) {
      STAGE_V(vbuf, (t + 1) * 64);
      if (t < 30) STAGE_K(kc, (t + 2) * 64);
    }
    f32x16 st0 = {};
    __builtin_amdgcn_s_setprio(1);
    st0 = __builtin_amdgcn_mfma_f32_32x32x16_bf16(kfn[0], qf[0], st0, 0, 0, 0);
    st0 = __builtin_amdgcn_mfma_f32_32x32x16_bf16(kfn[1], qf[1], st0, 0, 0, 0);
    st0 = __builtin_amdgcn_mfma_f32_32x32x16_bf16(kfn[2], qf[2], st0, 0, 0, 0);
    st0 = __builtin_amdgcn_mfma_f32_32x32x16_bf16(kfn[3], qf[3], st0, 0, 0, 0);
    __builtin_amdgcn_s_setprio(0);
    PV_PREV();
    if (t < 31) KF_PREFETCH(kbuf);
    SM_PACK(va);
    __syncthreads();
    bf16* tmp = ka; ka = kbuf; kbuf = kc; kc = tmp;
    bf16* tv = va; va = vbuf; vbuf = tv;
  }

  PV_PREV();

  // ---- combine partials across kv halves (within each q-group) ----
  // writers: tsel==1 (w&3 >= 2); readers: tsel==0. Pair shares (qgrp, qh).
  float* cb = (float*)smem;                   // 256 lanes-slots x 34 f32 = 34.8KB <= 40KB
  if (tsel == 1) {
    const int idx = ((qgrp * 2 + qh) * 64 + lane) * 34;
#pragma unroll
    for (int i = 0; i < 16; ++i) cb[idx + i] = o0[i];
#pragma unroll
    for (int i = 0; i < 16; ++i) cb[idx + 16 + i] = o1[i];
    cb[idx + 32] = lsum;
  }
  __syncthreads();
  if (tsel == 0) {
    const int idx = ((qgrp * 2 + qh) * 64 + lane) * 34;
#pragma unroll
    for (int i = 0; i < 16; ++i) o0[i] += cb[idx + i];
#pragma unroll
    for (int i = 0; i < 16; ++i) o1[i] += cb[idx + 16 + i];
    lsum += cb[idx + 32];
    lsum += __shfl_xor(lsum, 32);

    const float inv = 1.f / lsum;
    const int qrow = qblk * 128 + qgrp * 64 + qh * 32 + ql;
    bf16* outp = attnout + ((size_t)b * 2048 + qrow) * 1024 + h * 64;
#pragma unroll
    for (int j2 = 0; j2 < 4; ++j2) {
      bf16x4 ov;
#pragma unroll
      for (int jj = 0; jj < 4; ++jj) ov[jj] = f2bf(o0[j2 * 4 + jj] * inv);
      *(bf16x4*)(outp + j2 * 8 + hi * 4) = ov;
#pragma unroll
      for (int jj = 0; jj < 4; ++jj) ov[jj] = f2bf(o1[j2 * 4 + jj] * inv);
      *(bf16x4*)(outp + 32 + j2 * 8 + hi * 4) = ov;
    }
  }
#undef STAGE_K
#undef STAGE_V
#undef KF_PREFETCH
#undef SM_PACK
#undef PV_PREV
}

// ---------------- launch ----------------
extern "C" void kernel_launch(void* const* d_in, const int* in_sizes, int n_in,
                              void* d_out, int out_size, void* d_ws, size_t ws_size,
                              hipStream_t stream) {
  (void)in_sizes; (void)n_in; (void)out_size; (void)ws_size;
  const float* x    = (const float*)d_in[0];
  const float* p    = (const float*)d_in[1];
  const float* Wqkv = (const float*)d_in[2];
  const float* bqkv = (const float*)d_in[3];
  const float* Wout = (const float*)d_in[4];
  const float* bout = (const float*)d_in[5];
  const float* proj = (const float*)d_in[6];
  float* out = (float*)d_out;

  char* ws = (char*)d_ws;
  size_t off = 0;
  bf16* xb     = (bf16*)(ws + off); off += (size_t)4096 * 1024 * 2;
  bf16* pb     = (bf16*)(ws + off); off += (size_t)4096 * 1024 * 2;
  bf16* WqkvT  = (bf16*)(ws + off); off += (size_t)3072 * 1024 * 2;
  bf16* projT  = (bf16*)(ws + off); off += (size_t)512  * 1024 * 2;
  bf16* WoutT  = (bf16*)(ws + off); off += (size_t)1024 * 1024 * 2;
  float* phases= (float*)(ws + off); off += (size_t)4096 * 512 * 4;
  bf16* qb     = (bf16*)(ws + off); off += (size_t)4096 * 1024 * 2;
  bf16* kb     = (bf16*)(ws + off); off += (size_t)4096 * 1024 * 2;
  bf16* vb     = (bf16*)(ws + off); off += (size_t)4096 * 1024 * 2;
  bf16* attnb  = (bf16*)(ws + off); off += (size_t)4096 * 1024 * 2;

  k_prep<<<9344, 256, 0, stream>>>(x, xb, p, pb, Wqkv, WqkvT, proj, projT, Wout, WoutT);

  k_gemm128x64<<<dim3(32, 8), 512, 0, stream>>>(pb, projT, nullptr, phases, 4096, 512, 1024);
  k_gemm_qkv256<<<dim3(16, 12), 512, 0, stream>>>(xb, WqkvT, bqkv, phases, qb, kb, vb);

  k_flash_attn11<<<512, 512, 0, stream>>>(qb, kb, vb, attnb);

  k_gemm128x64<<<dim3(32, 16), 512, 0, stream>>>(attnb, WoutT, bout, out, 4096, 1024, 1024);
}